// Round 3
// baseline (1593.019 us; speedup 1.0000x reference)
//
#include <hip/hip_runtime.h>
#include <stdint.h>

typedef __bf16 bf16;
typedef __bf16 bf16x4v __attribute__((ext_vector_type(4)));
typedef __bf16 bf16x8 __attribute__((ext_vector_type(8)));
typedef float floatx4 __attribute__((ext_vector_type(4)));
typedef float float4v __attribute__((ext_vector_type(4)));

#define SCALE 0.17677669529663689f

// load input element i as float, honoring runtime dtype flag (1 = fp32, 0 = bf16)
__device__ __forceinline__ float ldin(const void* p, long i, int f32) {
  return f32 ? ((const float*)p)[i] : (float)(((const bf16*)p)[i]);
}

// ---------------- dtype detector ----------------
// bf16 N(0,1)-ish data: every nonzero uint16 word has a sane exponent field.
// fp32 data: low half-words have ~uniform random exponent fields -> many extremes.
__global__ void detect_k(const unsigned short* __restrict__ x, int* flag) {
  __shared__ int cnt;
  if (threadIdx.x == 0) cnt = 0;
  __syncthreads();
  int local = 0;
  for (int i = threadIdx.x; i < 4096; i += 256) {
    unsigned short w = x[i];
    int e = (w >> 7) & 0xFF;
    if (w != 0 && (e >= 0x9F || e <= 0x5F)) local++;
  }
  atomicAdd(&cnt, local);
  __syncthreads();
  if (threadIdx.x == 0) *flag = (cnt >= 64) ? 1 : 0;
}

// ---------------- weight convert+transpose: W[K][N] -> Wt[N][K] (bf16) ----------------
__global__ void conv_w_k(const void* __restrict__ W, bf16* __restrict__ Wt,
                         int K, int N, const int* __restrict__ flag) {
  int f32 = *flag;
  int idx = blockIdx.x * 256 + threadIdx.x;
  if (idx < K * N) {
    int k = idx / N, n = idx % N;
    Wt[n * K + k] = (bf16)ldin(W, idx, f32);
  }
}

// ---------------- LayerNorm: rows of 256, 1 wave per row ----------------
// x_input: 1 if x comes from d_in (dtype per flag), 0 if internal bf16
__global__ __launch_bounds__(256) void ln_k(const void* __restrict__ x,
                                            const void* __restrict__ g,
                                            const void* __restrict__ b,
                                            bf16* __restrict__ y,
                                            const int* __restrict__ flag,
                                            int x_input) {
  int f = *flag;
  int f32x = x_input ? f : 0;
  int wave = threadIdx.x >> 6, lane = threadIdx.x & 63;
  long row = (long)blockIdx.x * 4 + wave;
  float v[4];
  if (f32x) {
    float4v u = ((const float4v*)x)[row * 64 + lane];
    for (int i = 0; i < 4; i++) v[i] = u[i];
  } else {
    bf16x4v u = ((const bf16x4v*)x)[row * 64 + lane];
    for (int i = 0; i < 4; i++) v[i] = (float)u[i];
  }
  float s = v[0] + v[1] + v[2] + v[3];
  for (int off = 32; off > 0; off >>= 1) s += __shfl_xor(s, off, 64);
  float mean = s * (1.f / 256.f);
  float q = 0.f;
  for (int i = 0; i < 4; i++) { float d = v[i] - mean; q += d * d; }
  for (int off = 32; off > 0; off >>= 1) q += __shfl_xor(q, off, 64);
  float rstd = rsqrtf(q * (1.f / 256.f) + 1e-5f);
  bf16x4v o;
  for (int i = 0; i < 4; i++) {
    float gv = ldin(g, lane * 4 + i, f);
    float bv = ldin(b, lane * 4 + i, f);
    o[i] = (bf16)((v[i] - mean) * rstd * gv + bv);
  }
  ((bf16x4v*)y)[row * 64 + lane] = o;
}

// ------------- GEMM C[M][N] = A[M][K] @ Bt[N][K]^T + bias (+epilogue) -------------
// EPI: 0 = bias, 1 = bias+gelu(exact), 2 = bias+residual
// A, Bt internal bf16. bias from d_in (flag dtype). res/C dtype per res_input/out_input.
template <int EPI>
__global__ __launch_bounds__(256) void gemm_bt_k(
    const bf16* __restrict__ A, const bf16* __restrict__ Bt,
    const void* __restrict__ bias, const void* __restrict__ res,
    void* __restrict__ C, int M, int N, int K, const int* __restrict__ flag,
    int res_input, int out_input) {
  __shared__ bf16 As[128 * 32];
  __shared__ bf16 Bs[128 * 32];
  const int tid = threadIdx.x;
  const long m0 = (long)blockIdx.x * 128;
  const int n0 = blockIdx.y * 128;
  const int wave = tid >> 6, lane = tid & 63;
  const int wm = wave & 1, wn = wave >> 1;
  const int quad = lane >> 4, l16 = lane & 15;

  floatx4 acc[4][4];
  for (int i = 0; i < 4; i++)
    for (int j = 0; j < 4; j++) acc[i][j] = (floatx4){0.f, 0.f, 0.f, 0.f};

  const int ldr = tid >> 2;        // row within 64-row group
  const int ldc = (tid & 3) * 8;   // k-col start (8 bf16 = 16B)

  for (int kt = 0; kt < K; kt += 32) {
    bf16x8 a0 = *(const bf16x8*)(A + (m0 + ldr) * K + kt + ldc);
    bf16x8 a1 = *(const bf16x8*)(A + (m0 + 64 + ldr) * K + kt + ldc);
    bf16x8 b0 = *(const bf16x8*)(Bt + (long)(n0 + ldr) * K + kt + ldc);
    bf16x8 b1 = *(const bf16x8*)(Bt + (long)(n0 + 64 + ldr) * K + kt + ldc);
    __syncthreads();  // previous iter's LDS reads complete before overwrite
    *(bf16x8*)&As[tid * 8] = a0;
    *(bf16x8*)&As[(256 + tid) * 8] = a1;
    *(bf16x8*)&Bs[tid * 8] = b0;
    *(bf16x8*)&Bs[(256 + tid) * 8] = b1;
    __syncthreads();  // staged data visible
    bf16x8 af[4], bfr[4];
    for (int mi = 0; mi < 4; mi++)
      af[mi] = *(const bf16x8*)&As[(wm * 64 + mi * 16 + l16) * 32 + quad * 8];
    for (int ni = 0; ni < 4; ni++)
      bfr[ni] = *(const bf16x8*)&Bs[(wn * 64 + ni * 16 + l16) * 32 + quad * 8];
    for (int mi = 0; mi < 4; mi++)
      for (int ni = 0; ni < 4; ni++)
        acc[mi][ni] = __builtin_amdgcn_mfma_f32_16x16x32_bf16(
            af[mi], bfr[ni], acc[mi][ni], 0, 0, 0);
  }

  const int f = *flag;
  const int rf32 = res_input ? f : 0;
  const int of32 = out_input ? f : 0;
  for (int mi = 0; mi < 4; mi++) {
    for (int ni = 0; ni < 4; ni++) {
      int col = n0 + wn * 64 + ni * 16 + l16;
      float bv = ldin(bias, col, f);
      for (int r = 0; r < 4; r++) {
        long row = m0 + wm * 64 + mi * 16 + quad * 4 + r;
        float v = acc[mi][ni][r] + bv;
        if (EPI == 1) v = v * 0.5f * (1.f + erff(v * 0.70710678118654752f));
        if (EPI == 2) v += ldin(res, row * N + col, rf32);
        if (of32)
          ((float*)C)[row * N + col] = v;
        else
          ((bf16*)C)[row * N + col] = (bf16)v;
      }
    }
  }
}

// ---------------- windowed attention, 1 block per (window, head) ----------------
// qkv: [131072][768] token order (b*16384 + r*128 + c); o: [131072][256] (both bf16)
__global__ __launch_bounds__(256) void attn_k(const bf16* __restrict__ qkv,
                                              const void* __restrict__ rel_bias,
                                              bf16* __restrict__ o,
                                              const int* __restrict__ flag) {
  __shared__ float Qs[64][33], Ks[64][33], Vs[64][33];
  __shared__ float S[64][65];
  const int tid = threadIdx.x;
  const int head = blockIdx.x & 7;
  const int w = blockIdx.x >> 3;
  const int wx = w & 15, wy = (w >> 4) & 15, bb = w >> 8;
  const int f = *flag;

  for (int i = tid; i < 2048; i += 256) {
    int t = i >> 5, d = i & 31;
    int sy = wy * 8 + (t >> 3), sx = wx * 8 + (t & 7);
    int r = (sy + 4) & 127, c = (sx + 4) & 127;
    long base = ((long)bb * 16384 + r * 128 + c) * 768 + head * 32 + d;
    Qs[t][d] = (float)qkv[base];
    Ks[t][d] = (float)qkv[base + 256];
    Vs[t][d] = (float)qkv[base + 512];
  }
  __syncthreads();

  {  // S = scale * Q K^T + rel_bias  (each thread: 4x4 tile)
    int i0 = (tid >> 4) * 4, j0 = (tid & 15) * 4;
    float acc[4][4] = {};
    for (int kk = 0; kk < 32; kk++) {
      float qv[4], kv[4];
      for (int a = 0; a < 4; a++) qv[a] = Qs[i0 + a][kk];
      for (int b2 = 0; b2 < 4; b2++) kv[b2] = Ks[j0 + b2][kk];
      for (int a = 0; a < 4; a++)
        for (int b2 = 0; b2 < 4; b2++) acc[a][b2] += qv[a] * kv[b2];
    }
    for (int a = 0; a < 4; a++)
      for (int b2 = 0; b2 < 4; b2++) {
        int i = i0 + a, j = j0 + b2;
        int dy = (i >> 3) - (j >> 3) + 7, dx = (i & 7) - (j & 7) + 7;
        float bias = ldin(rel_bias, (dy * 15 + dx) * 8 + head, f);
        S[i][j] = acc[a][b2] * SCALE + bias;
      }
  }
  __syncthreads();

  if (tid < 64) {  // softmax over row tid
    float m = -1e30f;
    for (int j = 0; j < 64; j++) m = fmaxf(m, S[tid][j]);
    float sum = 0.f;
    for (int j = 0; j < 64; j++) {
      float e = __expf(S[tid][j] - m);
      S[tid][j] = e;
      sum += e;
    }
    float inv = 1.f / sum;
    for (int j = 0; j < 64; j++) S[tid][j] *= inv;
  }
  __syncthreads();

  {  // O = P V  (each thread: 4 rows x 2 cols)
    int ri = tid >> 4, ci = tid & 15;
    float acc[4][2] = {};
    for (int j = 0; j < 64; j++) {
      float v0 = Vs[j][ci * 2], v1 = Vs[j][ci * 2 + 1];
      for (int a = 0; a < 4; a++) {
        float p = S[ri * 4 + a][j];
        acc[a][0] += p * v0;
        acc[a][1] += p * v1;
      }
    }
    for (int a = 0; a < 4; a++) {
      int t = ri * 4 + a;
      int sy = wy * 8 + (t >> 3), sx = wx * 8 + (t & 7);
      int r = (sy + 4) & 127, c = (sx + 4) & 127;
      long base = ((long)bb * 16384 + r * 128 + c) * 256 + head * 32 + ci * 2;
      o[base] = (bf16)acc[a][0];
      o[base + 1] = (bf16)acc[a][1];
    }
  }
}

extern "C" void kernel_launch(void* const* d_in, const int* in_sizes, int n_in,
                              void* d_out, int out_size, void* d_ws,
                              size_t ws_size, hipStream_t stream) {
  const void* x = d_in[0];
  const void* n1g = d_in[1];
  const void* n1b = d_in[2];
  const void* qkv_w = d_in[3];
  const void* qkv_b = d_in[4];
  const void* rel_bias = d_in[5];
  const void* proj_w = d_in[6];
  const void* proj_b = d_in[7];
  const void* n2g = d_in[8];
  const void* n2b = d_in[9];
  const void* fc1_w = d_in[10];
  const void* fc1_b = d_in[11];
  const void* fc2_w = d_in[12];
  const void* fc2_b = d_in[13];

  char* ws = (char*)d_ws;
  int* flag = (int*)ws;
  bf16* qkvWt = (bf16*)(ws + 4096);           // 768*256 bf16
  bf16* projWt = qkvWt + 768 * 256;
  bf16* fc1Wt = projWt + 256 * 256;
  bf16* fc2Wt = fc1Wt + 256 * 256;
  bf16* reg1 = (bf16*)(ws + (1 << 20));                  // 64 MiB region
  bf16* reg2 = (bf16*)(ws + (1 << 20) + 67108864);       // 192 MiB region

  const int M = 131072;  // 8 * 16384 tokens

  detect_k<<<1, 256, 0, stream>>>((const unsigned short*)x, flag);

  conv_w_k<<<768, 256, 0, stream>>>(qkv_w, qkvWt, 256, 768, flag);
  conv_w_k<<<256, 256, 0, stream>>>(proj_w, projWt, 256, 256, flag);
  conv_w_k<<<256, 256, 0, stream>>>(fc1_w, fc1Wt, 256, 256, flag);
  conv_w_k<<<256, 256, 0, stream>>>(fc2_w, fc2Wt, 256, 256, flag);

  bf16* h = reg1;  // LN1 out
  ln_k<<<M / 4, 256, 0, stream>>>(x, n1g, n1b, h, flag, 1);

  bf16* qkv = reg2;  // [M][768]
  gemm_bt_k<0><<<dim3(M / 128, 6), 256, 0, stream>>>(
      h, qkvWt, qkv_b, nullptr, qkv, M, 768, 256, flag, 0, 0);

  bf16* o = reg1;  // overwrites h (dead)
  attn_k<<<2048 * 8, 256, 0, stream>>>(qkv, rel_bias, o, flag);

  bf16* x2 = reg2;  // overwrites qkv (dead)
  gemm_bt_k<2><<<dim3(M / 128, 2), 256, 0, stream>>>(
      o, projWt, proj_b, x, x2, M, 256, 256, flag, 1, 0);

  bf16* mbuf = reg1;  // overwrites o (dead)
  ln_k<<<M / 4, 256, 0, stream>>>(x2, n2g, n2b, mbuf, flag, 0);

  bf16* m1 = reg2 + 33554432;  // after x2 (64 MiB in)
  gemm_bt_k<1><<<dim3(M / 128, 2), 256, 0, stream>>>(
      mbuf, fc1Wt, fc1_b, nullptr, m1, M, 256, 256, flag, 0, 0);

  gemm_bt_k<2><<<dim3(M / 128, 2), 256, 0, stream>>>(
      m1, fc2Wt, fc2_b, x2, d_out, M, 256, 256, flag, 0, 1);
}

// Round 4
// 1079.836 us; speedup vs baseline: 1.4752x; 1.4752x over previous
//
#include <hip/hip_runtime.h>
#include <stdint.h>

typedef __bf16 bf16;
typedef __bf16 bf16x4v __attribute__((ext_vector_type(4)));
typedef __bf16 bf16x8 __attribute__((ext_vector_type(8)));
typedef float floatx4 __attribute__((ext_vector_type(4)));
typedef float float4v __attribute__((ext_vector_type(4)));

#define SCALE 0.17677669529663689f

// load input element i as float, honoring runtime dtype flag (1 = fp32, 0 = bf16)
__device__ __forceinline__ float ldin(const void* p, long i, int f32) {
  return f32 ? ((const float*)p)[i] : (float)(((const bf16*)p)[i]);
}

// ---------------- dtype detector ----------------
__global__ void detect_k(const unsigned short* __restrict__ x, int* flag) {
  __shared__ int cnt;
  if (threadIdx.x == 0) cnt = 0;
  __syncthreads();
  int local = 0;
  for (int i = threadIdx.x; i < 4096; i += 256) {
    unsigned short w = x[i];
    int e = (w >> 7) & 0xFF;
    if (w != 0 && (e >= 0x9F || e <= 0x5F)) local++;
  }
  atomicAdd(&cnt, local);
  __syncthreads();
  if (threadIdx.x == 0) *flag = (cnt >= 64) ? 1 : 0;
}

// ---------------- weight convert+transpose: W[K][N] -> Wt[N][K] (bf16) ----------------
__global__ void conv_w_k(const void* __restrict__ W, bf16* __restrict__ Wt,
                         int K, int N, const int* __restrict__ flag) {
  int f32 = *flag;
  int idx = blockIdx.x * 256 + threadIdx.x;
  if (idx < K * N) {
    int k = idx / N, n = idx % N;
    Wt[n * K + k] = (bf16)ldin(W, idx, f32);
  }
}

// ---------------- rel-bias precompute into MFMA C-order table ----------------
// bias_s[head][quad][l16][mi][ni][r]  (fp32, 32768 entries = 128 KB)
__global__ void bias_k(const void* __restrict__ rel, float* __restrict__ bias_s,
                       const int* __restrict__ flag) {
  int f = *flag;
  int idx = blockIdx.x * 256 + threadIdx.x;  // 0..32767
  int r = idx & 3, ni = (idx >> 2) & 3, mi = (idx >> 4) & 3;
  int l16 = (idx >> 6) & 15, quad = (idx >> 10) & 3, head = idx >> 12;
  int i = mi * 16 + quad * 4 + r, j = ni * 16 + l16;
  int dy = (i >> 3) - (j >> 3) + 7, dx = (i & 7) - (j & 7) + 7;
  bias_s[idx] = ldin(rel, (dy * 15 + dx) * 8 + head, f);
}

// ---------------- LayerNorm: rows of 256, 1 wave per row ----------------
__global__ __launch_bounds__(256) void ln_k(const void* __restrict__ x,
                                            const void* __restrict__ g,
                                            const void* __restrict__ b,
                                            bf16* __restrict__ y,
                                            const int* __restrict__ flag,
                                            int x_input) {
  int f = *flag;
  int f32x = x_input ? f : 0;
  int wave = threadIdx.x >> 6, lane = threadIdx.x & 63;
  long row = (long)blockIdx.x * 4 + wave;
  float v[4];
  if (f32x) {
    float4v u = ((const float4v*)x)[row * 64 + lane];
    for (int i = 0; i < 4; i++) v[i] = u[i];
  } else {
    bf16x4v u = ((const bf16x4v*)x)[row * 64 + lane];
    for (int i = 0; i < 4; i++) v[i] = (float)u[i];
  }
  float s = v[0] + v[1] + v[2] + v[3];
  for (int off = 32; off > 0; off >>= 1) s += __shfl_xor(s, off, 64);
  float mean = s * (1.f / 256.f);
  float q = 0.f;
  for (int i = 0; i < 4; i++) { float d = v[i] - mean; q += d * d; }
  for (int off = 32; off > 0; off >>= 1) q += __shfl_xor(q, off, 64);
  float rstd = rsqrtf(q * (1.f / 256.f) + 1e-5f);
  bf16x4v o;
  for (int i = 0; i < 4; i++) {
    float gv = ldin(g, lane * 4 + i, f);
    float bv = ldin(b, lane * 4 + i, f);
    o[i] = (bf16)((v[i] - mean) * rstd * gv + bv);
  }
  ((bf16x4v*)y)[row * 64 + lane] = o;
}

// ------------- GEMM C[M][N] = A[M][K] @ Bt[N][K]^T + bias (+epilogue) -------------
template <int EPI>
__global__ __launch_bounds__(256) void gemm_bt_k(
    const bf16* __restrict__ A, const bf16* __restrict__ Bt,
    const void* __restrict__ bias, const void* __restrict__ res,
    void* __restrict__ C, int M, int N, int K, const int* __restrict__ flag,
    int res_input, int out_input) {
  __shared__ bf16 As[128 * 32];
  __shared__ bf16 Bs[128 * 32];
  const int tid = threadIdx.x;
  const long m0 = (long)blockIdx.x * 128;
  const int n0 = blockIdx.y * 128;
  const int wave = tid >> 6, lane = tid & 63;
  const int wm = wave & 1, wn = wave >> 1;
  const int quad = lane >> 4, l16 = lane & 15;

  floatx4 acc[4][4];
  for (int i = 0; i < 4; i++)
    for (int j = 0; j < 4; j++) acc[i][j] = (floatx4){0.f, 0.f, 0.f, 0.f};

  const int ldr = tid >> 2;
  const int ldc = (tid & 3) * 8;

  for (int kt = 0; kt < K; kt += 32) {
    bf16x8 a0 = *(const bf16x8*)(A + (m0 + ldr) * K + kt + ldc);
    bf16x8 a1 = *(const bf16x8*)(A + (m0 + 64 + ldr) * K + kt + ldc);
    bf16x8 b0 = *(const bf16x8*)(Bt + (long)(n0 + ldr) * K + kt + ldc);
    bf16x8 b1 = *(const bf16x8*)(Bt + (long)(n0 + 64 + ldr) * K + kt + ldc);
    __syncthreads();
    *(bf16x8*)&As[tid * 8] = a0;
    *(bf16x8*)&As[(256 + tid) * 8] = a1;
    *(bf16x8*)&Bs[tid * 8] = b0;
    *(bf16x8*)&Bs[(256 + tid) * 8] = b1;
    __syncthreads();
    bf16x8 af[4], bfr[4];
    for (int mi = 0; mi < 4; mi++)
      af[mi] = *(const bf16x8*)&As[(wm * 64 + mi * 16 + l16) * 32 + quad * 8];
    for (int ni = 0; ni < 4; ni++)
      bfr[ni] = *(const bf16x8*)&Bs[(wn * 64 + ni * 16 + l16) * 32 + quad * 8];
    for (int mi = 0; mi < 4; mi++)
      for (int ni = 0; ni < 4; ni++)
        acc[mi][ni] = __builtin_amdgcn_mfma_f32_16x16x32_bf16(
            af[mi], bfr[ni], acc[mi][ni], 0, 0, 0);
  }

  const int f = *flag;
  const int rf32 = res_input ? f : 0;
  const int of32 = out_input ? f : 0;
  for (int mi = 0; mi < 4; mi++) {
    for (int ni = 0; ni < 4; ni++) {
      int col = n0 + wn * 64 + ni * 16 + l16;
      float bv = ldin(bias, col, f);
      for (int r = 0; r < 4; r++) {
        long row = m0 + wm * 64 + mi * 16 + quad * 4 + r;
        float v = acc[mi][ni][r] + bv;
        if (EPI == 1) v = v * 0.5f * (1.f + erff(v * 0.70710678118654752f));
        if (EPI == 2) v += ldin(res, row * N + col, rf32);
        if (of32)
          ((float*)C)[row * N + col] = v;
        else
          ((bf16*)C)[row * N + col] = (bf16)v;
      }
    }
  }
}

// ---------------- MFMA windowed attention ----------------
// 1 wave = 1 (window, head); block = 4 heads of same window.
// qkv: [131072][768] bf16; o: [131072][256] bf16; bias_s: MFMA C-order fp32.
__global__ __launch_bounds__(256) void attn_k(const bf16* __restrict__ qkv,
                                              const float* __restrict__ bias_s,
                                              bf16* __restrict__ o) {
  __shared__ bf16 Pb[4][64 * 64];
  __shared__ bf16 Vb[4][32 * 64];
  const int tid = threadIdx.x;
  const int wave = tid >> 6, lane = tid & 63;
  const int quad = lane >> 4, l16 = lane & 15;
  const int gid = blockIdx.x * 4 + wave;
  const int head = gid & 7, win = gid >> 3;
  const int wx = win & 15, wy = (win >> 4) & 15, bb = win >> 8;

  bf16* P = Pb[wave];
  bf16* Vt = Vb[wave];

  // --- load Q,K fragments direct from global; V natural -> LDS transposed ---
  bf16x8 qf[4], kf[4];
  for (int mi = 0; mi < 4; mi++) {
    int t = mi * 16 + l16;
    int rr = (wy * 8 + (t >> 3) + 4) & 127;
    int cc = (wx * 8 + (t & 7) + 4) & 127;
    long base = ((long)(bb * 16384 + rr * 128 + cc)) * 768 + head * 32 + quad * 8;
    qf[mi] = *(const bf16x8*)(qkv + base);
    kf[mi] = *(const bf16x8*)(qkv + base + 256);
    bf16x8 vv = *(const bf16x8*)(qkv + base + 512);
    // Vt[d][t] stored at d*64 + (t ^ ((d>>3)<<4)); here d = quad*8+jj, d>>3 = quad
    int tcol = t ^ (quad << 4);
    for (int jj = 0; jj < 8; jj++) Vt[(quad * 8 + jj) * 64 + tcol] = vv[jj];
  }
  __syncthreads();

  // --- S = Q K^T (16 MFMAs, K=32 single step) ---
  floatx4 acc[4][4];
  for (int mi = 0; mi < 4; mi++)
    for (int ni = 0; ni < 4; ni++) {
      floatx4 z = (floatx4){0.f, 0.f, 0.f, 0.f};
      acc[mi][ni] = __builtin_amdgcn_mfma_f32_16x16x32_bf16(qf[mi], kf[ni], z, 0, 0, 0);
    }

  // --- scale + bias + row softmax (rows live in one quad -> shfl over l16) ---
  const float4v* bp =
      (const float4v*)(bias_s + (((head * 4 + quad) * 16 + l16) << 6));
  for (int mi = 0; mi < 4; mi++) {
    float mx[4] = {-1e30f, -1e30f, -1e30f, -1e30f};
    for (int ni = 0; ni < 4; ni++) {
      float4v bv = bp[mi * 4 + ni];
      for (int r = 0; r < 4; r++) {
        acc[mi][ni][r] = acc[mi][ni][r] * SCALE + bv[r];
        mx[r] = fmaxf(mx[r], acc[mi][ni][r]);
      }
    }
    for (int r = 0; r < 4; r++) {
      float m = mx[r];
      for (int off = 1; off < 16; off <<= 1) m = fmaxf(m, __shfl_xor(m, off, 64));
      mx[r] = m;
    }
    float sm[4] = {0.f, 0.f, 0.f, 0.f};
    for (int ni = 0; ni < 4; ni++)
      for (int r = 0; r < 4; r++) {
        float e = __expf(acc[mi][ni][r] - mx[r]);
        acc[mi][ni][r] = e;
        sm[r] += e;
      }
    for (int r = 0; r < 4; r++) {
      float s = sm[r];
      for (int off = 1; off < 16; off <<= 1) s += __shfl_xor(s, off, 64);
      sm[r] = 1.f / s;
    }
    // P[i][j] stored at i*64 + (j ^ ((i&7)<<3))
    for (int ni = 0; ni < 4; ni++)
      for (int r = 0; r < 4; r++) {
        int i = mi * 16 + quad * 4 + r;
        int j = ni * 16 + l16;
        P[i * 64 + (j ^ ((i & 7) << 3))] = (bf16)(acc[mi][ni][r] * sm[r]);
      }
  }
  __syncthreads();

  // --- O = P V (16 MFMAs over 2 K-steps) ---
  floatx4 oacc[4][2];
  for (int mi = 0; mi < 4; mi++)
    for (int nt = 0; nt < 2; nt++) oacc[mi][nt] = (floatx4){0.f, 0.f, 0.f, 0.f};
  for (int ks = 0; ks < 2; ks++) {
    bf16x8 vfr[2];
    for (int nt = 0; nt < 2; nt++) {
      int d = nt * 16 + l16;
      vfr[nt] =
          *(const bf16x8*)&Vt[d * 64 + ((ks * 32 + quad * 8) ^ ((d >> 3) << 4))];
    }
    for (int mi = 0; mi < 4; mi++) {
      int i = mi * 16 + l16;
      bf16x8 pf =
          *(const bf16x8*)&P[i * 64 + ((ks * 32 + quad * 8) ^ ((i & 7) << 3))];
      for (int nt = 0; nt < 2; nt++)
        oacc[mi][nt] = __builtin_amdgcn_mfma_f32_16x16x32_bf16(pf, vfr[nt],
                                                               oacc[mi][nt], 0, 0, 0);
    }
  }

  // --- scatter O back (undo shift) ---
  for (int mi = 0; mi < 4; mi++)
    for (int r = 0; r < 4; r++) {
      int t = mi * 16 + quad * 4 + r;
      int rr = (wy * 8 + (t >> 3) + 4) & 127;
      int cc = (wx * 8 + (t & 7) + 4) & 127;
      long base = ((long)(bb * 16384 + rr * 128 + cc)) * 256 + head * 32 + l16;
      o[base] = (bf16)oacc[mi][0][r];
      o[base + 16] = (bf16)oacc[mi][1][r];
    }
}

extern "C" void kernel_launch(void* const* d_in, const int* in_sizes, int n_in,
                              void* d_out, int out_size, void* d_ws,
                              size_t ws_size, hipStream_t stream) {
  const void* x = d_in[0];
  const void* n1g = d_in[1];
  const void* n1b = d_in[2];
  const void* qkv_w = d_in[3];
  const void* qkv_b = d_in[4];
  const void* rel_bias = d_in[5];
  const void* proj_w = d_in[6];
  const void* proj_b = d_in[7];
  const void* n2g = d_in[8];
  const void* n2b = d_in[9];
  const void* fc1_w = d_in[10];
  const void* fc1_b = d_in[11];
  const void* fc2_w = d_in[12];
  const void* fc2_b = d_in[13];

  char* ws = (char*)d_ws;
  int* flag = (int*)ws;
  float* bias_s = (float*)(ws + 4096);        // 128 KB
  bf16* qkvWt = (bf16*)(ws + 262144);         // 768*256 bf16
  bf16* projWt = qkvWt + 768 * 256;
  bf16* fc1Wt = projWt + 256 * 256;
  bf16* fc2Wt = fc1Wt + 256 * 256;
  bf16* reg1 = (bf16*)(ws + (1 << 20));                  // 64 MiB region
  bf16* reg2 = (bf16*)(ws + (1 << 20) + 67108864);       // 192 MiB region

  const int M = 131072;  // 8 * 16384 tokens

  detect_k<<<1, 256, 0, stream>>>((const unsigned short*)x, flag);

  bias_k<<<128, 256, 0, stream>>>(rel_bias, bias_s, flag);
  conv_w_k<<<768, 256, 0, stream>>>(qkv_w, qkvWt, 256, 768, flag);
  conv_w_k<<<256, 256, 0, stream>>>(proj_w, projWt, 256, 256, flag);
  conv_w_k<<<256, 256, 0, stream>>>(fc1_w, fc1Wt, 256, 256, flag);
  conv_w_k<<<256, 256, 0, stream>>>(fc2_w, fc2Wt, 256, 256, flag);

  bf16* h = reg1;  // LN1 out
  ln_k<<<M / 4, 256, 0, stream>>>(x, n1g, n1b, h, flag, 1);

  bf16* qkv = reg2;  // [M][768]
  gemm_bt_k<0><<<dim3(M / 128, 6), 256, 0, stream>>>(
      h, qkvWt, qkv_b, nullptr, qkv, M, 768, 256, flag, 0, 0);

  bf16* o = reg1;  // overwrites h (dead)
  attn_k<<<2048 * 8 / 4, 256, 0, stream>>>(qkv, bias_s, o);

  bf16* x2 = reg2;  // overwrites qkv (dead)
  gemm_bt_k<2><<<dim3(M / 128, 2), 256, 0, stream>>>(
      o, projWt, proj_b, x, x2, M, 256, 256, flag, 1, 0);

  bf16* mbuf = reg1;  // overwrites o (dead)
  ln_k<<<M / 4, 256, 0, stream>>>(x2, n2g, n2b, mbuf, flag, 0);

  bf16* m1 = reg2 + 33554432;  // after x2 (64 MiB in)
  gemm_bt_k<1><<<dim3(M / 128, 2), 256, 0, stream>>>(
      mbuf, fc1Wt, fc1_b, nullptr, m1, M, 256, 256, flag, 0, 0);

  gemm_bt_k<2><<<dim3(M / 128, 2), 256, 0, stream>>>(
      m1, fc2Wt, fc2_b, x2, d_out, M, 256, 256, flag, 0, 1);
}